// Round 3
// baseline (268.076 us; speedup 1.0000x reference)
//
#include <hip/hip_runtime.h>
#include <hip/hip_cooperative_groups.h>
#include <math.h>

namespace cg = cooperative_groups;

#define CN 256
#define DN 512

typedef __attribute__((ext_vector_type(8))) short bf16x8;
typedef __attribute__((ext_vector_type(4))) float f32x4;

__device__ __forceinline__ short f2bf(float f) {
  unsigned u = __float_as_uint(f);
  u += 0x7fffu + ((u >> 16) & 1u);
  return (short)(u >> 16);
}
__device__ __forceinline__ bf16x8 pack8(float4 a, float4 b) {
  bf16x8 r;
  r[0] = f2bf(a.x); r[1] = f2bf(a.y); r[2] = f2bf(a.z); r[3] = f2bf(a.w);
  r[4] = f2bf(b.x); r[5] = f2bf(b.y); r[6] = f2bf(b.z); r[7] = f2bf(b.w);
  return r;
}
__device__ __forceinline__ float waveRed(float v) {
#pragma unroll
  for (int o = 32; o; o >>= 1) v += __shfl_down(v, o, 64);
  return v;
}
__device__ __forceinline__ float bRed(float v, float* red) {
  v = waveRed(v);
  __syncthreads();
  if ((threadIdx.x & 63) == 0) red[threadIdx.x >> 6] = v;
  __syncthreads();
  return red[0] + red[1] + red[2] + red[3];
}

// 64x64 tile MFMA GEMM, 4 waves (2x2), K-step 32, bf16 convert during staging.
// Fragment-major LDS: element (r,k) at short-index
// ((r>>4)<<9) + ((k>>3)<<7) + ((r&15)<<3) + (k&7)  -> wave operand load is a
// linear ds_read_b128 at group_base + lane*16 (conflict-free).
// BT=1: B is [N][K] (NT).  BT=0: B is [K][N] (NN, scatter-staged transpose).
template <int BT>
__device__ __forceinline__ void tile_gemm(const float* __restrict__ A,
                                          const float* __restrict__ B,
                                          int K, int N, int bm, int bn,
                                          short* As, short* Bs, f32x4 (&acc)[2][2]) {
  const int tid = threadIdx.x, lane = tid & 63, w = tid >> 6;
  const int wr = w >> 1, wc = w & 1;
  for (int k0 = 0; k0 < K; k0 += 32) {
    __syncthreads();
    {
      const int r = tid >> 2, q = tid & 3;
      const float4* pa = (const float4*)(A + (size_t)(bm + r) * K + k0 + (q << 3));
      *(bf16x8*)&As[((r >> 4) << 9) + (q << 7) + ((r & 15) << 3)] = pack8(pa[0], pa[1]);
    }
    if (BT) {
      const int n = tid >> 2, q = tid & 3;
      const float4* pb = (const float4*)(B + (size_t)(bn + n) * K + k0 + (q << 3));
      *(bf16x8*)&Bs[((n >> 4) << 9) + (q << 7) + ((n & 15) << 3)] = pack8(pb[0], pb[1]);
    } else {
      const int kr = tid >> 3, c = (tid & 7) << 3;
      const float4* pb = (const float4*)(B + (size_t)(k0 + kr) * N + bn + c);
      const float4 v0 = pb[0], v1 = pb[1];
      const float vv[8] = {v0.x, v0.y, v0.z, v0.w, v1.x, v1.y, v1.z, v1.w};
      const int kb = (kr >> 3) << 7, kl = kr & 7;
#pragma unroll
      for (int jx = 0; jx < 8; ++jx) {
        const int n = c + jx;
        Bs[((n >> 4) << 9) + kb + ((n & 15) << 3) + kl] = f2bf(vv[jx]);
      }
    }
    __syncthreads();
    const bf16x8 fa0 = *(const bf16x8*)&As[(((wr << 1) + 0) << 9) + (lane << 3)];
    const bf16x8 fa1 = *(const bf16x8*)&As[(((wr << 1) + 1) << 9) + (lane << 3)];
    const bf16x8 fb0 = *(const bf16x8*)&Bs[(((wc << 1) + 0) << 9) + (lane << 3)];
    const bf16x8 fb1 = *(const bf16x8*)&Bs[(((wc << 1) + 1) << 9) + (lane << 3)];
    acc[0][0] = __builtin_amdgcn_mfma_f32_16x16x32_bf16(fa0, fb0, acc[0][0], 0, 0, 0);
    acc[0][1] = __builtin_amdgcn_mfma_f32_16x16x32_bf16(fa0, fb1, acc[0][1], 0, 0, 0);
    acc[1][0] = __builtin_amdgcn_mfma_f32_16x16x32_bf16(fa1, fb0, acc[1][0], 0, 0, 0);
    acc[1][1] = __builtin_amdgcn_mfma_f32_16x16x32_bf16(fa1, fb1, acc[1][1], 0, 0, 0);
  }
}

// iterate the 2x2 fragment accumulator: binds r, c, v
#define EPI_LOOP(BODY) do { \
  const int lane_ = threadIdx.x & 63, ww_ = threadIdx.x >> 6; \
  const int wr_ = ww_ >> 1, wc_ = ww_ & 1; \
  _Pragma("unroll") for (int mi = 0; mi < 2; ++mi) \
  _Pragma("unroll") for (int ni = 0; ni < 2; ++ni) { \
    const int c = bn + (wc_ << 5) + (ni << 4) + (lane_ & 15); \
    const int rb = bm + (wr_ << 5) + (mi << 4) + ((lane_ >> 4) << 2); \
    _Pragma("unroll") for (int jx = 0; jx < 4; ++jx) { \
      const int r = rb + jx; const float v = acc[mi][ni][jx]; BODY; } \
  } } while (0)

struct Pk {
  const float *img_feature, *text, *img, *neg;
  const float *p_t, *aw_t, *ab_t, *p_i, *aw_i, *ab_i;
  const float *W_tt, *b_tt, *W_it, *b_it, *W_ntt, *b_ntt;
  float* out; float* ws;
};

__global__ __launch_bounds__(256) void mega_k(Pk p) {
  cg::grid_group grid = cg::this_grid();
  __shared__ __align__(16) short As[2048];
  __shared__ __align__(16) short Bs[2048];
  __shared__ float red[4];
  const int tid = threadIdx.x, bid = blockIdx.x;
  const int lane = tid & 63, wv = tid >> 6;

  float* ws   = p.ws;
  float* inv  = ws;              // 768 (text, img, neg inverse norms)
  float* srs  = ws + 768;        // 768
  float* Ecol = ws + 1536;       // 512
  float* d0   = ws + 2048;       // 768
  float* S_tt = ws + 4096;       // each [256,256]
  float* S_ii = S_tt + 65536;
  float* R_it = S_ii + 65536;
  float* S_nn = R_it + 65536;
  float* R_nt = S_nn + 65536;
  float* eT   = R_nt + 65536;
  float* eI   = eT + 65536;
  float* e0I  = eI + 65536;
  float* c_tt = e0I + 65536;
  float* c_it = c_tt + 65536;
  float* c_nt = c_it + 65536;
  float* h_t  = c_nt + 65536;
  float* h_i  = h_t + 65536;
  float* u_tt = h_i + 65536;     // each [256,512]
  float* u_it = u_tt + 131072;
  float* u_nt = u_it + 131072;

  // ---- S0: row inverse-norms of text/img/neg + img_feature passthrough ----
  {
#pragma unroll
    for (int z = 0; z < 3; ++z) {
      const float* src = z == 0 ? p.text : (z == 1 ? p.img : p.neg);
      const float x0 = src[bid * DN + tid];
      const float x1 = src[bid * DN + 256 + tid];
      const float ss = bRed(x0 * x0 + x1 * x1, red);
      if (tid == 0) inv[z * 256 + bid] = 1.f / fmaxf(sqrtf(ss), 1e-12f);
    }
    if (tid < 128) p.out[4 * CN * DN + bid * 128 + tid] = p.img_feature[bid * 128 + tid];
  }
  grid.sync();

  // ---- S1: 8 NT GEMMs (K=512, out 256x256): 5 cosine-sim + 3 exp-score ----
  if (bid < 128) {
    const int job = bid >> 4, tile = bid & 15;
    const int bm = (tile >> 2) << 6, bn = (tile & 3) << 6;
    const float* JA[8] = {p.text, p.img, p.text, p.neg, p.text, p.text, p.img, p.text};
    const float* JB[8] = {p.text, p.img, p.img,  p.neg, p.neg,  p.aw_t, p.aw_i, p.aw_i};
    float* JC[8] = {S_tt, S_ii, R_it, S_nn, R_nt, eT, eI, e0I};
    f32x4 acc[2][2] = {};
    tile_gemm<1>(JA[job], JB[job], 512, 256, bm, bn, As, Bs, acc);
    float* C = JC[job];
    if (job < 5) {
      const float* SAt[5] = {inv, inv + 256, inv,       inv + 512, inv};
      const float* SBt[5] = {inv, inv + 256, inv + 256, inv + 512, inv + 512};
      const float* sA = SAt[job];
      const float* sB = SBt[job];
      EPI_LOOP(C[(size_t)r * CN + c] = v * sA[r] * sB[c]);
    } else {
      const float* bias = job == 5 ? p.ab_t : p.ab_i;
      EPI_LOOP(C[(size_t)r * CN + c] = expf(v + bias[c]));
    }
  }
  grid.sync();

  // ---- S2: srs (768 relu-rowsum tasks) + Ecol (512 colsum tasks), wave-level ----
  for (int t = bid * 4 + wv; t < 1280; t += 1024) {
    if (t < 768) {
      const int z = t >> 8, b = t & 255;
      const float* S = z == 0 ? S_tt : (z == 1 ? S_ii : S_nn);
      float s = 0.f;
#pragma unroll
      for (int i = 0; i < 4; ++i) s += fmaxf(S[b * CN + lane + i * 64], 0.f);
      s = waveRed(s);
      if (lane == 0) srs[t] = 1.f + s;
    } else {
      const int t2 = t - 768, z = t2 >> 8, cc = t2 & 255;
      const float* e = z ? eI : eT;
      float s = 0.f;
#pragma unroll
      for (int i = 0; i < 4; ++i) s += e[(lane + i * 64) * CN + cc];
      s = waveRed(s);
      if (lane == 0) Ecol[t2] = s;
    }
  }
  grid.sync();

  // ---- S3: c coefficients + d0 (3 block-tasks per block) ----
  {
#pragma unroll
    for (int z = 0; z < 3; ++z) {
      const float* R = z == 0 ? S_tt : (z == 1 ? R_it : R_nt);
      float* cM = z == 0 ? c_tt : (z == 1 ? c_it : c_nt);
      const float rv = fmaxf(R[bid * CN + tid], 0.f);
      cM[bid * CN + tid] = rv * rsqrtf(srs[z * 256 + tid] + rv);
      const float s = bRed(rv, red);
      if (tid == 0) d0[z * 256 + bid] = rsqrtf(2.f + s);
    }
  }
  grid.sync();

  // ---- S4: g = c @ e (NN, K=256) fused with h epilogue ----
  if (bid < 32) {
    const int job = bid >> 4, tile = bid & 15;
    const int bm = (tile >> 2) << 6, bn = (tile & 3) << 6;
    const float* A = job ? c_it : c_tt;
    const float* B = job ? eI : eT;
    const float* e0 = job ? e0I : eT;
    const float* E = Ecol + job * 256;
    const float* dz = d0 + job * 256;
    float* H = job ? h_i : h_t;
    f32x4 acc[2][2] = {};
    tile_gemm<0>(A, B, 256, 256, bm, bn, As, Bs, acc);
    EPI_LOOP({
      const size_t idx = (size_t)r * CN + c;
      const float e = e0[idx];
      H[idx] = (2.f * dz[r] * e + v) / (e + E[c]);
    });
  }
  grid.sync();

  // ---- S5: u = h@p_list + c@shared + 2*d0*text (NN, K=256, N=512) ----
  if (bid < 96) {
    const int job = bid >> 5, t = bid & 31;
    const int bm = (t >> 3) << 6, bn = (t & 7) << 6;
    f32x4 acc[2][2] = {};
    const float* dz; float* U;
    if (job == 0) {
      tile_gemm<0>(h_t, p.p_t, 256, 512, bm, bn, As, Bs, acc);
      tile_gemm<0>(c_tt, p.text, 256, 512, bm, bn, As, Bs, acc);
      dz = d0; U = u_tt;
    } else if (job == 1) {
      tile_gemm<0>(h_i, p.p_i, 256, 512, bm, bn, As, Bs, acc);
      tile_gemm<0>(c_it, p.img, 256, 512, bm, bn, As, Bs, acc);
      dz = d0 + 256; U = u_it;
    } else {
      tile_gemm<0>(c_nt, p.neg, 256, 512, bm, bn, As, Bs, acc);
      dz = d0 + 512; U = u_nt;
    }
    EPI_LOOP({
      const size_t idx = (size_t)r * DN + c;
      U[idx] = v + 2.f * dz[r] * p.text[idx];
    });
  }
  grid.sync();

  // ---- S6: out = tanh(d0*(u@W) + bias) (NN, K=512, N=512) -> d_out slots ----
  if (bid < 96) {
    const int job = bid >> 5, t = bid & 31;
    const int bm = (t >> 3) << 6, bn = (t & 7) << 6;
    const float* A = job == 0 ? u_tt : (job == 1 ? u_it : u_nt);
    const float* W = job == 0 ? p.W_tt : (job == 1 ? p.W_it : p.W_ntt);
    const float* bias = job == 0 ? p.b_tt : (job == 1 ? p.b_it : p.b_ntt);
    const float* dz = d0 + job * 256;
    float* O = p.out + (size_t)(job + 1) * CN * DN;
    f32x4 acc[2][2] = {};
    tile_gemm<0>(A, W, 512, 512, bm, bn, As, Bs, acc);
    EPI_LOOP({
      const size_t idx = (size_t)r * DN + c;
      O[idx] = tanhf(dz[r] * v + bias[idx]);
    });
  }
  grid.sync();

  // ---- S7: main = 0.5*text + 0.35*o_tt + 0.15*o_it ----
  {
    const float* o1 = p.out + CN * DN;
    const float* o2 = p.out + 2 * CN * DN;
#pragma unroll
    for (int it = 0; it < 2; ++it) {
      const int i = bid * 512 + it * 256 + tid;
      p.out[i] = 0.5f * p.text[i] + 0.35f * o1[i] + 0.15f * o2[i];
    }
  }
}

extern "C" void kernel_launch(void* const* d_in, const int* in_sizes, int n_in,
                              void* d_out, int out_size, void* d_ws, size_t ws_size,
                              hipStream_t stream) {
  Pk prm;
  prm.img_feature = (const float*)d_in[0];
  prm.text  = (const float*)d_in[1];
  prm.img   = (const float*)d_in[2];
  prm.neg   = (const float*)d_in[3];
  prm.p_t   = (const float*)d_in[4];
  prm.aw_t  = (const float*)d_in[5];
  prm.ab_t  = (const float*)d_in[6];
  prm.p_i   = (const float*)d_in[7];
  prm.aw_i  = (const float*)d_in[8];
  prm.ab_i  = (const float*)d_in[9];
  prm.W_tt  = (const float*)d_in[10];
  prm.b_tt  = (const float*)d_in[11];
  prm.W_it  = (const float*)d_in[12];
  prm.b_it  = (const float*)d_in[13];
  prm.W_ntt = (const float*)d_in[14];
  prm.b_ntt = (const float*)d_in[15];
  prm.out = (float*)d_out;
  prm.ws  = (float*)d_ws;
  void* args[] = {&prm};
  hipLaunchCooperativeKernel((void*)mega_k, dim3(256), dim3(256), args, 0, stream);
}

// Round 4
// 88.819 us; speedup vs baseline: 3.0182x; 3.0182x over previous
//
#include <hip/hip_runtime.h>
#include <math.h>

#define CN 256
#define DN 512

typedef __attribute__((ext_vector_type(8))) short bf16x8;
typedef __attribute__((ext_vector_type(4))) float f32x4;

__device__ __forceinline__ short f2bf(float f) {
  unsigned u = __float_as_uint(f);
  u += 0x7fffu + ((u >> 16) & 1u);
  return (short)(u >> 16);
}

struct Pk {
  const float *img_feature, *text, *img, *neg;
  const float *p_t, *aw_t, *ab_t, *p_i, *aw_i, *ab_i;
  const float *W_tt, *b_tt, *W_it, *b_it, *W_ntt, *b_ntt;
  float* out; float* ws;
};

// ---- workspace layout (floats) ----
// 0        S_tt  [256x256]
// 65536    S_ii
// 131072   R_it
// 196608   S_nn
// 262144   R_nt
// 327680   eT
// 393216   eI
// 458752   e0I
// 524288   h_t
// 589824   h_i
// 655360   u_tt [256x512]
// 786432   u_it
// 917504   u_nt
// 1048576  rp[5][8][256]  relu-row-sum partials (S_tt,S_ii,R_it,S_nn,R_nt)
// 1058816  ec[2][8][256]  exp col-sum partials (eT,eI)
#define WS_S    0
#define WS_E    327680
#define WS_H    524288
#define WS_U    655360
#define WS_RP   1048576
#define WS_EC   1058816

// fragment-major LDS index for element (r,k) of a 64x32 tile
#define FMI(r, k) (((r) >> 4 << 9) + ((k) >> 3 << 7) + (((r) & 15) << 3) + ((k) & 7))

__device__ __forceinline__ void mfma4(const short* As, const short* Bs, int wr, int wc,
                                      int lane, f32x4 (&acc)[2][2]) {
  const bf16x8 fa0 = *(const bf16x8*)&As[(((wr << 1) + 0) << 9) + (lane << 3)];
  const bf16x8 fa1 = *(const bf16x8*)&As[(((wr << 1) + 1) << 9) + (lane << 3)];
  const bf16x8 fb0 = *(const bf16x8*)&Bs[(((wc << 1) + 0) << 9) + (lane << 3)];
  const bf16x8 fb1 = *(const bf16x8*)&Bs[(((wc << 1) + 1) << 9) + (lane << 3)];
  acc[0][0] = __builtin_amdgcn_mfma_f32_16x16x32_bf16(fa0, fb0, acc[0][0], 0, 0, 0);
  acc[0][1] = __builtin_amdgcn_mfma_f32_16x16x32_bf16(fa0, fb1, acc[0][1], 0, 0, 0);
  acc[1][0] = __builtin_amdgcn_mfma_f32_16x16x32_bf16(fa1, fb0, acc[1][0], 0, 0, 0);
  acc[1][1] = __builtin_amdgcn_mfma_f32_16x16x32_bf16(fa1, fb1, acc[1][1], 0, 0, 0);
}

// NN GEMM tile pass: A [M][K] row-major, B [K][N] row-major (scatter-transposed).
// TRA=1: A-staging applies c-transform relu(x)*rsqrt(srs_lds[k]+relu(x)).
template <int TRA>
__device__ __forceinline__ void gemm_nn(const float* __restrict__ A,
                                        const float* __restrict__ B,
                                        int K, int N, int bm, int bn,
                                        short* As, short* Bs,
                                        const float* srs_lds, f32x4 (&acc)[2][2]) {
  const int tid = threadIdx.x, lane = tid & 63, w = tid >> 6;
  const int wr = w >> 1, wc = w & 1;
  for (int k0 = 0; k0 < K; k0 += 32) {
    __syncthreads();
    {
      const int r = tid >> 2, q = tid & 3;
      const float* pa = A + (size_t)(bm + r) * K + k0 + (q << 3);
      float x[8];
      *(float4*)&x[0] = *(const float4*)pa;
      *(float4*)&x[4] = *(const float4*)(pa + 4);
      bf16x8 pk;
#pragma unroll
      for (int i = 0; i < 8; ++i) {
        float v = x[i];
        if (TRA) { const float rv = fmaxf(v, 0.f); v = rv * rsqrtf(srs_lds[k0 + (q << 3) + i] + rv); }
        pk[i] = f2bf(v);
      }
      *(bf16x8*)&As[FMI(r, 0) + (q << 7)] = pk;
    }
    {
      const int kr = tid >> 3, c = (tid & 7) << 3;
      const float* pb = B + (size_t)(k0 + kr) * N + bn + c;
      float x[8];
      *(float4*)&x[0] = *(const float4*)pb;
      *(float4*)&x[4] = *(const float4*)(pb + 4);
      const int kb = (kr >> 3) << 7, kl = kr & 7;
#pragma unroll
      for (int j = 0; j < 8; ++j) {
        const int n = c + j;
        Bs[((n >> 4) << 9) + kb + ((n & 15) << 3) + kl] = f2bf(x[j]);
      }
    }
    __syncthreads();
    mfma4(As, Bs, wr, wc, lane, acc);
  }
}

// ---- Stage 1: 8 NT GEMMs (K=512) + fused norms + row/col partial sums ----
__global__ __launch_bounds__(256) void s1_k(Pk p) {
  __shared__ __align__(16) short As[2048];
  __shared__ __align__(16) short Bs[2048];
  __shared__ float ssl[2][64][4];
  __shared__ float invA[64], invB[64];
  const int bid = blockIdx.x, tid = threadIdx.x;
  const int job = bid >> 4, tile = bid & 15;
  const int bm = (tile >> 2) << 6, bn = (tile & 3) << 6;
  const int lane = tid & 63, w = tid >> 6, wr = w >> 1, wc = w & 1;
  float* ws = p.ws;

  const float* JA[8] = {p.text, p.img, p.text, p.neg, p.text, p.text, p.img, p.text};
  const float* JB[8] = {p.text, p.img, p.img,  p.neg, p.neg,  p.aw_t, p.aw_i, p.aw_i};
  float* C = ws + WS_S + job * 65536;
  const float* A = JA[job];
  const float* B = JB[job];

  // img_feature passthrough (128 blocks x 256 thr = 32768 elements)
  p.out[4 * CN * DN + bid * 256 + tid] = p.img_feature[bid * 256 + tid];

  f32x4 acc[2][2] = {};
  float ssa = 0.f, ssb = 0.f;
  for (int k0 = 0; k0 < 512; k0 += 32) {
    __syncthreads();
    {
      const int r = tid >> 2, q = tid & 3;
      const float* pa = A + (size_t)(bm + r) * 512 + k0 + (q << 3);
      float x[8];
      *(float4*)&x[0] = *(const float4*)pa;
      *(float4*)&x[4] = *(const float4*)(pa + 4);
      bf16x8 pk;
#pragma unroll
      for (int i = 0; i < 8; ++i) { ssa += x[i] * x[i]; pk[i] = f2bf(x[i]); }
      *(bf16x8*)&As[FMI(r, 0) + (q << 7)] = pk;
    }
    {
      const int n = tid >> 2, q = tid & 3;
      const float* pb = B + (size_t)(bn + n) * 512 + k0 + (q << 3);
      float x[8];
      *(float4*)&x[0] = *(const float4*)pb;
      *(float4*)&x[4] = *(const float4*)(pb + 4);
      bf16x8 pk;
#pragma unroll
      for (int i = 0; i < 8; ++i) { ssb += x[i] * x[i]; pk[i] = f2bf(x[i]); }
      *(bf16x8*)&Bs[FMI(n, 0) + (q << 7)] = pk;
    }
    __syncthreads();
    mfma4(As, Bs, wr, wc, lane, acc);
  }

  // reduce norms
  __syncthreads();
  ssl[0][tid >> 2][tid & 3] = ssa;
  ssl[1][tid >> 2][tid & 3] = ssb;
  __syncthreads();
  if (tid < 64) {
    const float s = ssl[0][tid][0] + ssl[0][tid][1] + ssl[0][tid][2] + ssl[0][tid][3];
    invA[tid] = 1.f / fmaxf(sqrtf(s), 1e-12f);
  } else if (tid < 128) {
    const int t = tid - 64;
    const float s = ssl[1][t][0] + ssl[1][t][1] + ssl[1][t][2] + ssl[1][t][3];
    invB[t] = 1.f / fmaxf(sqrtf(s), 1e-12f);
  }
  __syncthreads();

  // epilogue
  float sv[2][2][4];
  if (job < 5) {
#pragma unroll
    for (int mi = 0; mi < 2; ++mi)
#pragma unroll
      for (int ni = 0; ni < 2; ++ni) {
        const int cl = (wc << 5) + (ni << 4) + (lane & 15);
#pragma unroll
        for (int jx = 0; jx < 4; ++jx) {
          const int rl = (wr << 5) + (mi << 4) + ((lane >> 4) << 2) + jx;
          const float v = acc[mi][ni][jx] * invA[rl] * invB[cl];
          sv[mi][ni][jx] = v;
          C[(size_t)(bm + rl) * CN + bn + cl] = v;
        }
      }
    // relu row-sum partials (32-col wave quadrant) -> rp[job][tc][row]
    float* rp = ws + WS_RP + job * 2048 + ((bn >> 5) + wc) * 256;
#pragma unroll
    for (int mi = 0; mi < 2; ++mi)
#pragma unroll
      for (int jx = 0; jx < 4; ++jx) {
        float s = fmaxf(sv[mi][0][jx], 0.f) + fmaxf(sv[mi][1][jx], 0.f);
        s += __shfl_xor(s, 1, 64); s += __shfl_xor(s, 2, 64);
        s += __shfl_xor(s, 4, 64); s += __shfl_xor(s, 8, 64);
        if ((lane & 15) == 0) {
          const int rl = (wr << 5) + (mi << 4) + ((lane >> 4) << 2) + jx;
          rp[bm + rl] = s;
        }
      }
  } else {
    const float* bias = (job == 5) ? p.ab_t : p.ab_i;
#pragma unroll
    for (int mi = 0; mi < 2; ++mi)
#pragma unroll
      for (int ni = 0; ni < 2; ++ni) {
        const int cl = (wc << 5) + (ni << 4) + (lane & 15);
#pragma unroll
        for (int jx = 0; jx < 4; ++jx) {
          const int rl = (wr << 5) + (mi << 4) + ((lane >> 4) << 2) + jx;
          const float v = expf(acc[mi][ni][jx] + bias[bn + cl]);
          sv[mi][ni][jx] = v;
          C[(size_t)(bm + rl) * CN + bn + cl] = v;
        }
      }
    if (job < 7) {  // exp col-sum partials (32-row wave quadrant) -> ec[z][tr][col]
      float* ec = ws + WS_EC + (job - 5) * 2048 + ((bm >> 5) + wr) * 256;
#pragma unroll
      for (int ni = 0; ni < 2; ++ni) {
        float s = 0.f;
#pragma unroll
        for (int mi = 0; mi < 2; ++mi)
#pragma unroll
          for (int jx = 0; jx < 4; ++jx) s += sv[mi][ni][jx];
        s += __shfl_xor(s, 16, 64); s += __shfl_xor(s, 32, 64);
        if ((lane >> 4) == 0) {
          const int cl = (wc << 5) + (ni << 4) + (lane & 15);
          ec[bn + cl] = s;
        }
      }
    }
  }
}

// ---- Stage 2: g = c@e with on-the-fly c, fused h epilogue ----
__global__ __launch_bounds__(256) void s2_k(Pk p) {
  __shared__ __align__(16) short As[2048];
  __shared__ __align__(16) short Bs[2048];
  __shared__ float srs_lds[256], d0_lds[64], E_lds[64];
  const int bid = blockIdx.x, tid = threadIdx.x;
  const int job = bid >> 4, tile = bid & 15;
  const int bm = (tile >> 2) << 6, bn = (tile & 3) << 6;
  const int lane = tid & 63, w = tid >> 6, wr = w >> 1, wc = w & 1;
  float* ws = p.ws;

  const float* Araw = ws + WS_S + (job ? 2 : 0) * 65536;   // S_tt / R_it
  const float* Bm   = ws + WS_E + (job ? 1 : 0) * 65536;   // eT / eI
  const float* e0   = ws + WS_E + (job ? 2 : 0) * 65536;   // eT / e0I
  const int srsmat = job ? 1 : 0;                          // S_tt / S_ii rowsums
  const int d0mat  = job ? 2 : 0;                          // S_tt / R_it rowsums
  float* H = ws + WS_H + job * 65536;

  {
    const float* rp = ws + WS_RP + srsmat * 2048;
    float s = 1.f;
#pragma unroll
    for (int tc = 0; tc < 8; ++tc) s += rp[tc * 256 + tid];
    srs_lds[tid] = s;
  }
  if (tid < 64) {
    const float* rp = ws + WS_RP + d0mat * 2048;
    float s = 2.f;
#pragma unroll
    for (int tc = 0; tc < 8; ++tc) s += rp[tc * 256 + bm + tid];
    d0_lds[tid] = rsqrtf(s);
  } else if (tid < 128) {
    const float* ec = ws + WS_EC + job * 2048;
    float s = 0.f;
#pragma unroll
    for (int tr = 0; tr < 8; ++tr) s += ec[tr * 256 + bn + (tid - 64)];
    E_lds[tid - 64] = s;
  }

  f32x4 acc[2][2] = {};
  gemm_nn<1>(Araw, Bm, 256, 256, bm, bn, As, Bs, srs_lds, acc);

#pragma unroll
  for (int mi = 0; mi < 2; ++mi)
#pragma unroll
    for (int ni = 0; ni < 2; ++ni) {
      const int cl = (wc << 5) + (ni << 4) + (lane & 15);
#pragma unroll
      for (int jx = 0; jx < 4; ++jx) {
        const int rl = (wr << 5) + (mi << 4) + ((lane >> 4) << 2) + jx;
        const size_t idx = (size_t)(bm + rl) * CN + bn + cl;
        const float e = e0[idx];
        H[idx] = (2.f * d0_lds[rl] * e + acc[mi][ni][jx]) / (e + E_lds[cl]);
      }
    }
}

// ---- Stage 3: u = h@p_list + c@shared + 2*d0*text ----
__global__ __launch_bounds__(256) void s3_k(Pk p) {
  __shared__ __align__(16) short As[2048];
  __shared__ __align__(16) short Bs[2048];
  __shared__ float srs_lds[256], d0_lds[64];
  const int bid = blockIdx.x, tid = threadIdx.x;
  const int job = bid >> 5, t = bid & 31;
  const int bm = (t >> 3) << 6, bn = (t & 7) << 6;
  const int lane = tid & 63, w = tid >> 6, wr = w >> 1, wc = w & 1;
  float* ws = p.ws;

  const int srsmat = (job == 0) ? 0 : (job == 1 ? 1 : 3);
  const int d0mat  = (job == 0) ? 0 : (job == 1 ? 2 : 4);
  {
    const float* rp = ws + WS_RP + srsmat * 2048;
    float s = 1.f;
#pragma unroll
    for (int tc = 0; tc < 8; ++tc) s += rp[tc * 256 + tid];
    srs_lds[tid] = s;
  }
  if (tid < 64) {
    const float* rp = ws + WS_RP + d0mat * 2048;
    float s = 2.f;
#pragma unroll
    for (int tc = 0; tc < 8; ++tc) s += rp[tc * 256 + bm + tid];
    d0_lds[tid] = rsqrtf(s);
  }

  f32x4 acc[2][2] = {};
  float* U;
  if (job == 0) {
    gemm_nn<0>(ws + WS_H, p.p_t, 256, 512, bm, bn, As, Bs, srs_lds, acc);
    gemm_nn<1>(ws + WS_S, p.text, 256, 512, bm, bn, As, Bs, srs_lds, acc);
    U = ws + WS_U;
  } else if (job == 1) {
    gemm_nn<0>(ws + WS_H + 65536, p.p_i, 256, 512, bm, bn, As, Bs, srs_lds, acc);
    gemm_nn<1>(ws + WS_S + 2 * 65536, p.img, 256, 512, bm, bn, As, Bs, srs_lds, acc);
    U = ws + WS_U + 131072;
  } else {
    gemm_nn<1>(ws + WS_S + 4 * 65536, p.neg, 256, 512, bm, bn, As, Bs, srs_lds, acc);
    U = ws + WS_U + 262144;
  }

#pragma unroll
  for (int mi = 0; mi < 2; ++mi)
#pragma unroll
    for (int ni = 0; ni < 2; ++ni) {
      const int cl = (wc << 5) + (ni << 4) + (lane & 15);
#pragma unroll
      for (int jx = 0; jx < 4; ++jx) {
        const int rl = (wr << 5) + (mi << 4) + ((lane >> 4) << 2) + jx;
        const size_t idx = (size_t)(bm + rl) * DN + bn + cl;
        U[idx] = acc[mi][ni][jx] + 2.f * d0_lds[rl] * p.text[idx];
      }
    }
}

// ---- Stage 4: out slots 1-3 = tanh(d0*(u@W)+bias); job3 = main combine ----
__global__ __launch_bounds__(256) void s4_k(Pk p) {
  __shared__ __align__(16) short As[2048];
  __shared__ __align__(16) short Bs[2048];
  __shared__ float d0a_lds[64], d0b_lds[64];
  const int bid = blockIdx.x, tid = threadIdx.x;
  const int job = bid >> 5, t = bid & 31;
  const int bm = (t >> 3) << 6, bn = (t & 7) << 6;
  const int lane = tid & 63, w = tid >> 6, wr = w >> 1, wc = w & 1;
  float* ws = p.ws;

  const int d0A = (job == 0 || job == 3) ? 0 : (job == 1 ? 2 : 4);
  if (tid < 64) {
    const float* rp = ws + WS_RP + d0A * 2048;
    float s = 2.f;
#pragma unroll
    for (int tc = 0; tc < 8; ++tc) s += rp[tc * 256 + bm + tid];
    d0a_lds[tid] = rsqrtf(s);
    if (job == 3) {
      const float* rp2 = ws + WS_RP + 2 * 2048;
      float s2 = 2.f;
#pragma unroll
      for (int tc = 0; tc < 8; ++tc) s2 += rp2[tc * 256 + bm + tid];
      d0b_lds[tid] = rsqrtf(s2);
    }
  }

  if (job < 3) {
    const float* A = ws + WS_U + job * 131072;
    const float* W = (job == 0) ? p.W_tt : (job == 1 ? p.W_it : p.W_ntt);
    const float* bias = (job == 0) ? p.b_tt : (job == 1 ? p.b_it : p.b_ntt);
    float* O = p.out + (size_t)(job + 1) * CN * DN;
    f32x4 acc[2][2] = {};
    gemm_nn<0>(A, W, 512, 512, bm, bn, As, Bs, nullptr, acc);
#pragma unroll
    for (int mi = 0; mi < 2; ++mi)
#pragma unroll
      for (int ni = 0; ni < 2; ++ni) {
        const int cl = (wc << 5) + (ni << 4) + (lane & 15);
#pragma unroll
        for (int jx = 0; jx < 4; ++jx) {
          const int rl = (wr << 5) + (mi << 4) + ((lane >> 4) << 2) + jx;
          const size_t idx = (size_t)(bm + rl) * DN + bn + cl;
          O[idx] = tanhf(d0a_lds[rl] * acc[mi][ni][jx] + bias[idx]);
        }
      }
  } else {
    f32x4 acc1[2][2] = {}, acc2[2][2] = {};
    gemm_nn<0>(ws + WS_U, p.W_tt, 512, 512, bm, bn, As, Bs, nullptr, acc1);
    gemm_nn<0>(ws + WS_U + 131072, p.W_it, 512, 512, bm, bn, As, Bs, nullptr, acc2);
#pragma unroll
    for (int mi = 0; mi < 2; ++mi)
#pragma unroll
      for (int ni = 0; ni < 2; ++ni) {
        const int cl = (wc << 5) + (ni << 4) + (lane & 15);
#pragma unroll
        for (int jx = 0; jx < 4; ++jx) {
          const int rl = (wr << 5) + (mi << 4) + ((lane >> 4) << 2) + jx;
          const size_t idx = (size_t)(bm + rl) * DN + bn + cl;
          const float ott = tanhf(d0a_lds[rl] * acc1[mi][ni][jx] + p.b_tt[idx]);
          const float oit = tanhf(d0b_lds[rl] * acc2[mi][ni][jx] + p.b_it[idx]);
          p.out[idx] = 0.5f * p.text[idx] + 0.35f * ott + 0.15f * oit;
        }
      }
  }
}

extern "C" void kernel_launch(void* const* d_in, const int* in_sizes, int n_in,
                              void* d_out, int out_size, void* d_ws, size_t ws_size,
                              hipStream_t stream) {
  Pk prm;
  prm.img_feature = (const float*)d_in[0];
  prm.text  = (const float*)d_in[1];
  prm.img   = (const float*)d_in[2];
  prm.neg   = (const float*)d_in[3];
  prm.p_t   = (const float*)d_in[4];
  prm.aw_t  = (const float*)d_in[5];
  prm.ab_t  = (const float*)d_in[6];
  prm.p_i   = (const float*)d_in[7];
  prm.aw_i  = (const float*)d_in[8];
  prm.ab_i  = (const float*)d_in[9];
  prm.W_tt  = (const float*)d_in[10];
  prm.b_tt  = (const float*)d_in[11];
  prm.W_it  = (const float*)d_in[12];
  prm.b_it  = (const float*)d_in[13];
  prm.W_ntt = (const float*)d_in[14];
  prm.b_ntt = (const float*)d_in[15];
  prm.out = (float*)d_out;
  prm.ws  = (float*)d_ws;

  s1_k<<<128, 256, 0, stream>>>(prm);
  s2_k<<<32, 256, 0, stream>>>(prm);
  s3_k<<<96, 256, 0, stream>>>(prm);
  s4_k<<<128, 256, 0, stream>>>(prm);
}

// Round 5
// 65.584 us; speedup vs baseline: 4.0875x; 1.3543x over previous
//
#include <hip/hip_runtime.h>
#include <math.h>

#define CN 256
#define DN 512

typedef __attribute__((ext_vector_type(8))) short bf16x8;
typedef __attribute__((ext_vector_type(4))) short bf16x4;
typedef __attribute__((ext_vector_type(4))) float f32x4;

__device__ __forceinline__ short f2bf(float f) {
  unsigned u = __float_as_uint(f);
  u += 0x7fffu + ((u >> 16) & 1u);
  return (short)(u >> 16);
}

struct Pk {
  const float *img_feature, *text, *img, *neg;
  const float *p_t, *aw_t, *ab_t, *p_i, *aw_i, *ab_i;
  const float *W_tt, *b_tt, *W_it, *b_it, *W_ntt, *b_ntt;
  float* out; float* ws;
};

// ---- f32 workspace (float offsets) ----
#define WF_S   0          // 5 x 65536 : S_tt, S_ii, R_it, S_nn, R_nt
#define WF_E   327680     // 3 x 65536 : eT, eI, e0I
#define WF_RP  524288     // 5 x 2048  : relu row-sum partials
#define WF_EC  534528     // 2 x 2048  : exp col-sum partials
#define WF_INV 538624     // 3 x 256   : inverse row norms
#define WF_BF  540672     // bf16 region start (float offset)

// ---- bf16 panel region (short offsets from SH) ----
// panel form for X[R][K]: 64-row strips, per strip K/32 tiles of 2048 shorts;
// within tile, local (r,k) at ((r>>4)<<9)+((k>>3)<<7)+((r&15)<<3)+(k&7)
#define SB_PLAIN 0          // 5 x 131072 : text, img, neg, aw_t, aw_i   [256][512]
#define SB_WT    655360     // 3 x 262144 : W_tt^T, W_it^T, W_ntt^T      [512][512]
#define SB_XT    1441792    // 3 x 131072 : text^T, img^T, neg^T         [512][256]
#define SB_PT    1835008    // 2 x 131072 : p_t^T, p_i^T                 [512][256]
#define SB_ETP   2097152    // 2 x 65536  : eT^T, eI^T                   [256][256]
#define SB_CP    2228224    // 3 x 65536  : c_tt, c_it, c_nt             [256][256]
#define SB_HP    2424832    // 2 x 65536  : h_t, h_i                     [256][256]
#define SB_UP    2555904    // 3 x 131072 : u_tt, u_it, u_nt             [256][512]

__device__ __forceinline__ void mfma_tiles(const short* at, const short* bt,
                                           int wr, int wc, int lane, f32x4 (&acc)[2][2]) {
  const bf16x8 fa0 = *(const bf16x8*)(at + ((wr << 1) << 9) + (lane << 3));
  const bf16x8 fa1 = *(const bf16x8*)(at + (((wr << 1) + 1) << 9) + (lane << 3));
  const bf16x8 fb0 = *(const bf16x8*)(bt + ((wc << 1) << 9) + (lane << 3));
  const bf16x8 fb1 = *(const bf16x8*)(bt + (((wc << 1) + 1) << 9) + (lane << 3));
  acc[0][0] = __builtin_amdgcn_mfma_f32_16x16x32_bf16(fa0, fb0, acc[0][0], 0, 0, 0);
  acc[0][1] = __builtin_amdgcn_mfma_f32_16x16x32_bf16(fa0, fb1, acc[0][1], 0, 0, 0);
  acc[1][0] = __builtin_amdgcn_mfma_f32_16x16x32_bf16(fa1, fb0, acc[1][0], 0, 0, 0);
  acc[1][1] = __builtin_amdgcn_mfma_f32_16x16x32_bf16(fa1, fb1, acc[1][1], 0, 0, 0);
}

__device__ __forceinline__ void reg_nt_gemm(const short* Astrip, const short* Bstrip,
                                            int ntiles, int wr, int wc, int lane,
                                            f32x4 (&acc)[2][2]) {
#pragma unroll 4
  for (int ks = 0; ks < ntiles; ++ks)
    mfma_tiles(Astrip + ks * 2048, Bstrip + ks * 2048, wr, wc, lane, acc);
}

// ---- P0: pre-convert + pre-tile all operands, compute row inv-norms ----
__global__ __launch_bounds__(256) void p0_k(Pk p) {
  short* SH = (short*)(p.ws + WF_BF);
  const int bid = blockIdx.x, tid = threadIdx.x;
  if (bid < 20) {  // plain panels: {text,img,neg,aw_t,aw_i} x 4 strips
    const int mat = bid >> 2, pr = bid & 3;
    const float* X = (mat == 0) ? p.text : (mat == 1) ? p.img : (mat == 2) ? p.neg
                     : (mat == 3) ? p.aw_t : p.aw_i;
    short* Y = SH + SB_PLAIN + mat * 131072 + pr * 32768;
    const int rloc = tid >> 2, q = tid & 3;
    const int r = pr * 64 + rloc;
    float ss = 0.f;
#pragma unroll
    for (int i = 0; i < 16; ++i) {
      const int k0 = q * 8 + i * 32;
      const float4 v0 = *(const float4*)(X + (size_t)r * 512 + k0);
      const float4 v1 = *(const float4*)(X + (size_t)r * 512 + k0 + 4);
      bf16x8 pk;
      pk[0] = f2bf(v0.x); pk[1] = f2bf(v0.y); pk[2] = f2bf(v0.z); pk[3] = f2bf(v0.w);
      pk[4] = f2bf(v1.x); pk[5] = f2bf(v1.y); pk[6] = f2bf(v1.z); pk[7] = f2bf(v1.w);
      ss += v0.x*v0.x + v0.y*v0.y + v0.z*v0.z + v0.w*v0.w
          + v1.x*v1.x + v1.y*v1.y + v1.z*v1.z + v1.w*v1.w;
      *(bf16x8*)(Y + i * 2048 + ((rloc >> 4) << 9) + (q << 7) + ((rloc & 15) << 3)) = pk;
    }
    if (mat < 3) {
      ss += __shfl_xor(ss, 1, 64);
      ss += __shfl_xor(ss, 2, 64);
      if (q == 0) p.ws[WF_INV + mat * 256 + r] = 1.f / fmaxf(sqrtf(ss), 1e-12f);
    }
  } else {  // transposed panels
    const float* X; short* Y; int K;
    if (bid < 44)      { const int m = (bid-20)>>3, pr = (bid-20)&7;
                         X = (m==0)?p.W_tt:(m==1)?p.W_it:p.W_ntt;
                         Y = SH + SB_WT + m*262144 + pr*32768; K = 512; }
    else if (bid < 68) { const int m = (bid-44)>>3, pr = (bid-44)&7;
                         X = (m==0)?p.text:(m==1)?p.img:p.neg;
                         Y = SH + SB_XT + m*131072 + pr*16384; K = 256; }
    else               { const int m = (bid-68)>>3, pr = (bid-68)&7;
                         X = (m==0)?p.p_t:p.p_i;
                         Y = SH + SB_PT + m*131072 + pr*16384; K = 256; }
    const int lane = tid & 63, wv = tid >> 6;
    const int pr_ = (bid < 44) ? ((bid-20)&7) : (bid < 68) ? ((bid-44)&7) : ((bid-68)&7);
    const int d = pr_ * 64 + lane;
    const int nch = K >> 5;
    for (int c = 0; c < nch; ++c) {
      const int m0 = wv * (K >> 2) + c * 8;
      bf16x8 pk;
#pragma unroll
      for (int j = 0; j < 8; ++j) pk[j] = f2bf(X[(size_t)(m0 + j) * 512 + d]);
      *(bf16x8*)(Y + (m0 >> 5) * 2048 + ((lane >> 4) << 9) + (((m0 >> 3) & 3) << 7)
                 + ((lane & 15) << 3)) = pk;
    }
  }
}

// ---- S1: 8 register-NT GEMMs (K=512) + scaled/exp epilogues + partials ----
__global__ __launch_bounds__(256) void s1_k(Pk p) {
  float* ws = p.ws;
  short* SH = (short*)(ws + WF_BF);
  const int bid = blockIdx.x, tid = threadIdx.x;
  const int job = bid >> 4, tile = bid & 15;
  const int bm = (tile >> 2) << 6, bn = (tile & 3) << 6;
  const int lane = tid & 63, w = tid >> 6, wr = w >> 1, wc = w & 1;

  p.out[4 * CN * DN + bid * 256 + tid] = p.img_feature[bid * 256 + tid];

  const int AM[8] = {0, 1, 0, 2, 0, 0, 1, 0};
  const int BM[8] = {0, 1, 1, 2, 2, 3, 4, 4};
  const short* Astrip = SH + SB_PLAIN + AM[job] * 131072 + (bm >> 6) * 32768;
  const short* Bstrip = SH + SB_PLAIN + BM[job] * 131072 + (bn >> 6) * 32768;
  f32x4 acc[2][2] = {};
  reg_nt_gemm(Astrip, Bstrip, 16, wr, wc, lane, acc);

  float sv[2][2][4];
  if (job < 5) {
    const float* invA = ws + WF_INV + AM[job] * 256;
    const float* invB = ws + WF_INV + BM[job] * 256;
    float* C = ws + WF_S + job * 65536;
#pragma unroll
    for (int mi = 0; mi < 2; ++mi)
#pragma unroll
      for (int ni = 0; ni < 2; ++ni) {
        const int cl = (wc << 5) + (ni << 4) + (lane & 15);
#pragma unroll
        for (int jx = 0; jx < 4; ++jx) {
          const int rl = (wr << 5) + (mi << 4) + ((lane >> 4) << 2) + jx;
          const float v = acc[mi][ni][jx] * invA[bm + rl] * invB[bn + cl];
          sv[mi][ni][jx] = v;
          C[(size_t)(bm + rl) * CN + bn + cl] = v;
        }
      }
    float* rp = ws + WF_RP + job * 2048 + ((bn >> 5) + wc) * 256;
#pragma unroll
    for (int mi = 0; mi < 2; ++mi)
#pragma unroll
      for (int jx = 0; jx < 4; ++jx) {
        float s = fmaxf(sv[mi][0][jx], 0.f) + fmaxf(sv[mi][1][jx], 0.f);
        s += __shfl_xor(s, 1, 64); s += __shfl_xor(s, 2, 64);
        s += __shfl_xor(s, 4, 64); s += __shfl_xor(s, 8, 64);
        if ((lane & 15) == 0) {
          const int rl = (wr << 5) + (mi << 4) + ((lane >> 4) << 2) + jx;
          rp[bm + rl] = s;
        }
      }
  } else {
    const int z = job - 5;
    const float* bias = (job == 5) ? p.ab_t : p.ab_i;
    float* C = ws + WF_E + z * 65536;
#pragma unroll
    for (int mi = 0; mi < 2; ++mi)
#pragma unroll
      for (int ni = 0; ni < 2; ++ni) {
        const int cl = (wc << 5) + (ni << 4) + (lane & 15);
        const int rb = (wr << 5) + (mi << 4) + ((lane >> 4) << 2);
#pragma unroll
        for (int jx = 0; jx < 4; ++jx) {
          const float v = expf(acc[mi][ni][jx] + bias[bn + cl]);
          sv[mi][ni][jx] = v;
          C[(size_t)(bm + rb + jx) * CN + bn + cl] = v;
        }
        if (z < 2) {  // transposed bf16 panel write (e^T)
          bf16x4 pk;
#pragma unroll
          for (int jx = 0; jx < 4; ++jx) pk[jx] = f2bf(sv[mi][ni][jx]);
          short* ET = SH + SB_ETP + z * 65536 + (bn >> 6) * 16384 + (bm >> 5) * 2048;
          const int idx = (rb >> 5) * 2048 + ((cl >> 4) << 9) + (((rb & 31) >> 3) << 7)
                        + ((cl & 15) << 3) + (rb & 7);
          *(bf16x4*)(ET + idx) = pk;
        }
      }
    if (z < 2) {
      float* ec = ws + WF_EC + z * 2048 + ((bm >> 5) + wr) * 256;
#pragma unroll
      for (int ni = 0; ni < 2; ++ni) {
        float s = 0.f;
#pragma unroll
        for (int mi = 0; mi < 2; ++mi)
#pragma unroll
          for (int jx = 0; jx < 4; ++jx) s += sv[mi][ni][jx];
        s += __shfl_xor(s, 16, 64); s += __shfl_xor(s, 32, 64);
        if ((lane >> 4) == 0) ec[bn + (wc << 5) + (ni << 4) + (lane & 15)] = s;
      }
    }
  }
}

// ---- S2: g-GEMM (c on-the-fly in LDS, e^T panels register) + h->hP;
//          plus cP panel builder jobs ----
__global__ __launch_bounds__(256) void s2_k(Pk p) {
  float* ws = p.ws;
  short* SH = (short*)(ws + WF_BF);
  __shared__ __align__(16) short As[2048];
  __shared__ float srs_lds[256], d0_lds[64], E_lds[64];
  const int bid = blockIdx.x, tid = threadIdx.x;

  if (bid < 32) {
    const int job = bid >> 4, tile = bid & 15;
    const int bm = (tile >> 2) << 6, bn = (tile & 3) << 6;
    const int lane = tid & 63, w = tid >> 6, wr = w >> 1, wc = w & 1;
    const float* Araw = ws + WF_S + (job ? 2 : 0) * 65536;   // S_tt / R_it
    const float* e0   = ws + WF_E + (job ? 2 : 0) * 65536;   // eT / e0I
    const short* Bbase = SH + SB_ETP + job * 65536 + (bn >> 6) * 16384;
    {
      const float* rp = ws + WF_RP + (job ? 1 : 0) * 2048;
      float s = 1.f;
#pragma unroll
      for (int tc = 0; tc < 8; ++tc) s += rp[tc * 256 + tid];
      srs_lds[tid] = s;
    }
    if (tid < 64) {
      const float* rp = ws + WF_RP + (job ? 2 : 0) * 2048;
      float s = 2.f;
#pragma unroll
      for (int tc = 0; tc < 8; ++tc) s += rp[tc * 256 + bm + tid];
      d0_lds[tid] = rsqrtf(s);
    } else if (tid < 128) {
      const float* ec = ws + WF_EC + job * 2048;
      float s = 0.f;
#pragma unroll
      for (int tr = 0; tr < 8; ++tr) s += ec[tr * 256 + bn + (tid - 64)];
      E_lds[tid - 64] = s;
    }
    f32x4 acc[2][2] = {};
    for (int k0 = 0; k0 < 256; k0 += 32) {
      __syncthreads();
      const int r = tid >> 2, q = tid & 3;
      const float* pa = Araw + (size_t)(bm + r) * 256 + k0 + (q << 3);
      float x[8];
      *(float4*)&x[0] = *(const float4*)pa;
      *(float4*)&x[4] = *(const float4*)(pa + 4);
      bf16x8 pk;
#pragma unroll
      for (int i = 0; i < 8; ++i) {
        const float rv = fmaxf(x[i], 0.f);
        pk[i] = f2bf(rv * rsqrtf(srs_lds[k0 + (q << 3) + i] + rv));
      }
      *(bf16x8*)(As + ((r >> 4) << 9) + (q << 7) + ((r & 15) << 3)) = pk;
      __syncthreads();
      mfma_tiles(As, Bbase + (k0 >> 5) * 2048, wr, wc, lane, acc);
    }
    short* HP = SH + SB_HP + job * 65536 + (bm >> 6) * 16384 + (bn >> 5) * 2048;
#pragma unroll
    for (int mi = 0; mi < 2; ++mi)
#pragma unroll
      for (int ni = 0; ni < 2; ++ni) {
        const int cl = (wc << 5) + (ni << 4) + (lane & 15);
        const int rb = (wr << 5) + (mi << 4) + ((lane >> 4) << 2);
#pragma unroll
        for (int jx = 0; jx < 4; ++jx) {
          const int rl = rb + jx;
          const size_t gi = (size_t)(bm + rl) * CN + bn + cl;
          const float e = e0[gi];
          const float hv = (2.f * d0_lds[rl] * e + acc[mi][ni][jx]) / (e + E_lds[cl]);
          HP[(cl >> 5) * 2048 + ((rl >> 4) << 9) + (((cl & 31) >> 3) << 7)
             + ((rl & 15) << 3) + (cl & 7)] = f2bf(hv);
        }
      }
  } else {  // cP builders: 3 mats x 4 strips
    const int t2 = bid - 32, z = t2 >> 2, pr = t2 & 3;
    const int SRC[3] = {0, 2, 4};
    const int SRS[3] = {0, 1, 3};
    const float* src = ws + WF_S + SRC[z] * 65536;
    {
      const float* rp = ws + WF_RP + SRS[z] * 2048;
      float s = 1.f;
#pragma unroll
      for (int tc = 0; tc < 8; ++tc) s += rp[tc * 256 + tid];
      srs_lds[tid] = s;
    }
    __syncthreads();
    short* Y = SH + SB_CP + z * 65536 + pr * 16384;
    const int rloc = tid >> 2, q = tid & 3, r = pr * 64 + rloc;
#pragma unroll
    for (int i = 0; i < 8; ++i) {
      const int k0 = q * 8 + i * 32;
      float x[8];
      *(float4*)&x[0] = *(const float4*)(src + (size_t)r * 256 + k0);
      *(float4*)&x[4] = *(const float4*)(src + (size_t)r * 256 + k0 + 4);
      bf16x8 pk;
#pragma unroll
      for (int j = 0; j < 8; ++j) {
        const float rv = fmaxf(x[j], 0.f);
        pk[j] = f2bf(rv * rsqrtf(srs_lds[k0 + j] + rv));
      }
      *(bf16x8*)(Y + i * 2048 + ((rloc >> 4) << 9) + (q << 7) + ((rloc & 15) << 3)) = pk;
    }
  }
}

// ---- S3: u = h@p^T-panels + c@x^T-panels + 2*d0*text -> uP ----
__global__ __launch_bounds__(256) void s3_k(Pk p) {
  float* ws = p.ws;
  short* SH = (short*)(ws + WF_BF);
  __shared__ float d0_lds[64];
  const int bid = blockIdx.x, tid = threadIdx.x;
  const int job = bid >> 5, t = bid & 31;
  const int bm = (t >> 3) << 6, bn = (t & 7) << 6;
  const int lane = tid & 63, w = tid >> 6, wr = w >> 1, wc = w & 1;
  const int D0M[3] = {0, 2, 4};
  if (tid < 64) {
    const float* rp = ws + WF_RP + D0M[job] * 2048;
    float s = 2.f;
#pragma unroll
    for (int tc = 0; tc < 8; ++tc) s += rp[tc * 256 + bm + tid];
    d0_lds[tid] = rsqrtf(s);
  }
  __syncthreads();
  f32x4 acc[2][2] = {};
  if (job == 0) {
    reg_nt_gemm(SH + SB_HP + (bm >> 6) * 16384, SH + SB_PT + (bn >> 6) * 16384, 8, wr, wc, lane, acc);
    reg_nt_gemm(SH + SB_CP + (bm >> 6) * 16384, SH + SB_XT + (bn >> 6) * 16384, 8, wr, wc, lane, acc);
  } else if (job == 1) {
    reg_nt_gemm(SH + SB_HP + 65536 + (bm >> 6) * 16384, SH + SB_PT + 131072 + (bn >> 6) * 16384, 8, wr, wc, lane, acc);
    reg_nt_gemm(SH + SB_CP + 65536 + (bm >> 6) * 16384, SH + SB_XT + 131072 + (bn >> 6) * 16384, 8, wr, wc, lane, acc);
  } else {
    reg_nt_gemm(SH + SB_CP + 131072 + (bm >> 6) * 16384, SH + SB_XT + 262144 + (bn >> 6) * 16384, 8, wr, wc, lane, acc);
  }
  short* UP = SH + SB_UP + job * 131072 + (bm >> 6) * 32768 + (bn >> 5) * 2048;
#pragma unroll
  for (int mi = 0; mi < 2; ++mi)
#pragma unroll
    for (int ni = 0; ni < 2; ++ni) {
      const int cl = (wc << 5) + (ni << 4) + (lane & 15);
      const int rb = (wr << 5) + (mi << 4) + ((lane >> 4) << 2);
#pragma unroll
      for (int jx = 0; jx < 4; ++jx) {
        const int rl = rb + jx;
        const float uv = acc[mi][ni][jx]
                       + 2.f * d0_lds[rl] * p.text[(size_t)(bm + rl) * DN + bn + cl];
        UP[(cl >> 5) * 2048 + ((rl >> 4) << 9) + (((cl & 31) >> 3) << 7)
           + ((rl & 15) << 3) + (cl & 7)] = f2bf(uv);
      }
    }
}

// ---- S4: out = tanh(d0*(u@W)+bias); job3 computes main combine ----
__global__ __launch_bounds__(256) void s4_k(Pk p) {
  float* ws = p.ws;
  short* SH = (short*)(ws + WF_BF);
  __shared__ float d0a[64], d0b[64];
  const int bid = blockIdx.x, tid = threadIdx.x;
  const int job = bid >> 5, t = bid & 31;
  const int bm = (t >> 3) << 6, bn = (t & 7) << 6;
  const int lane = tid & 63, w = tid >> 6, wr = w >> 1, wc = w & 1;
  const int D0A[4] = {0, 2, 4, 0};
  if (tid < 64) {
    const float* rp = ws + WF_RP + D0A[job] * 2048;
    float s = 2.f;
#pragma unroll
    for (int tc = 0; tc < 8; ++tc) s += rp[tc * 256 + bm + tid];
    d0a[tid] = rsqrtf(s);
    if (job == 3) {
      const float* rp2 = ws + WF_RP + 2 * 2048;
      float s2 = 2.f;
#pragma unroll
      for (int tc = 0; tc < 8; ++tc) s2 += rp2[tc * 256 + bm + tid];
      d0b[tid] = rsqrtf(s2);
    }
  }
  __syncthreads();

  if (job < 3) {
    const float* bias = (job == 0) ? p.b_tt : (job == 1) ? p.b_it : p.b_ntt;
    float* O = p.out + (size_t)(job + 1) * CN * DN;
    f32x4 acc[2][2] = {};
    reg_nt_gemm(SH + SB_UP + job * 131072 + (bm >> 6) * 32768,
                SH + SB_WT + job * 262144 + (bn >> 6) * 32768, 16, wr, wc, lane, acc);
#pragma unroll
    for (int mi = 0; mi < 2; ++mi)
#pragma unroll
      for (int ni = 0; ni < 2; ++ni) {
        const int cl = (wc << 5) + (ni << 4) + (lane & 15);
        const int rb = (wr << 5) + (mi << 4) + ((lane >> 4) << 2);
#pragma unroll
        for (int jx = 0; jx < 4; ++jx) {
          const int rl = rb + jx;
          const size_t idx = (size_t)(bm + rl) * DN + bn + cl;
          O[idx] = tanhf(d0a[rl] * acc[mi][ni][jx] + bias[idx]);
        }
      }
  } else {
    f32x4 acc1[2][2] = {}, acc2[2][2] = {};
    reg_nt_gemm(SH + SB_UP + (bm >> 6) * 32768,
                SH + SB_WT + (bn >> 6) * 32768, 16, wr, wc, lane, acc1);
    reg_nt_gemm(SH + SB_UP + 131072 + (bm >> 6) * 32768,
                SH + SB_WT + 262144 + (bn >> 6) * 32768, 16, wr, wc, lane, acc2);
#pragma unroll
    for (int mi = 0; mi < 2; ++mi)
#pragma unroll
      for (int ni = 0; ni < 2; ++ni) {
        const int cl = (wc << 5) + (ni << 4) + (lane & 15);
        const int rb = (wr << 5) + (mi << 4) + ((lane >> 4) << 2);
#pragma unroll
        for (int jx = 0; jx < 4; ++jx) {
          const int rl = rb + jx;
          const size_t idx = (size_t)(bm + rl) * DN + bn + cl;
          const float ott = tanhf(d0a[rl] * acc1[mi][ni][jx] + p.b_tt[idx]);
          const float oit = tanhf(d0b[rl] * acc2[mi][ni][jx] + p.b_it[idx]);
          p.out[idx] = 0.5f * p.text[idx] + 0.35f * ott + 0.15f * oit;
        }
      }
  }
}

extern "C" void kernel_launch(void* const* d_in, const int* in_sizes, int n_in,
                              void* d_out, int out_size, void* d_ws, size_t ws_size,
                              hipStream_t stream) {
  Pk prm;
  prm.img_feature = (const float*)d_in[0];
  prm.text  = (const float*)d_in[1];
  prm.img   = (const float*)d_in[2];
  prm.neg   = (const float*)d_in[3];
  prm.p_t   = (const float*)d_in[4];
  prm.aw_t  = (const float*)d_in[5];
  prm.ab_t  = (const float*)d_in[6];
  prm.p_i   = (const float*)d_in[7];
  prm.aw_i  = (const float*)d_in[8];
  prm.ab_i  = (const float*)d_in[9];
  prm.W_tt  = (const float*)d_in[10];
  prm.b_tt  = (const float*)d_in[11];
  prm.W_it  = (const float*)d_in[12];
  prm.b_it  = (const float*)d_in[13];
  prm.W_ntt = (const float*)d_in[14];
  prm.b_ntt = (const float*)d_in[15];
  prm.out = (float*)d_out;
  prm.ws  = (float*)d_ws;

  p0_k<<<84, 256, 0, stream>>>(prm);
  s1_k<<<128, 256, 0, stream>>>(prm);
  s2_k<<<44, 256, 0, stream>>>(prm);
  s3_k<<<96, 256, 0, stream>>>(prm);
  s4_k<<<128, 256, 0, stream>>>(prm);
}

// Round 6
// 58.037 us; speedup vs baseline: 4.6191x; 1.1300x over previous
//
#include <hip/hip_runtime.h>
#include <math.h>

#define CN 256
#define DN 512

typedef __attribute__((ext_vector_type(8))) short bf16x8;
typedef __attribute__((ext_vector_type(4))) short bf16x4;
typedef __attribute__((ext_vector_type(4))) float f32x4;

__device__ __forceinline__ short f2bf(float f) {
  unsigned u = __float_as_uint(f);
  u += 0x7fffu + ((u >> 16) & 1u);
  return (short)(u >> 16);
}

struct Pk {
  const float *img_feature, *text, *img, *neg;
  const float *p_t, *aw_t, *ab_t, *p_i, *aw_i, *ab_i;
  const float *W_tt, *b_tt, *W_it, *b_it, *W_ntt, *b_ntt;
  float* out; float* ws;
};

// ---- f32 workspace (float offsets) ----
#define WF_S   0          // 5 x 65536 : S_tt, S_ii, R_it, S_nn, R_nt
#define WF_E   327680     // 3 x 65536 : eT, eI, e0I
#define WF_RP  524288     // 5 x 2048  : relu row-sum partials
#define WF_EC  534528     // 2 x 2048  : exp col-sum partials
#define WF_INV 538624     // 3 x 256
#define WF_TW  540672     // 3 x 131072 : text@W_tt, text@W_it, text@W_ntt (f32)
#define WF_BF  933888     // bf16 region start

// ---- bf16 panel region (short offsets) ----
// panel for X[R][K]: 64-row strips (64*K shorts each); strip = K/32 tiles of
// 2048; within tile (r,k): ((r>>4)<<9)+((k>>3)<<7)+((r&15)<<3)+(k&7)
#define SB_PLAIN 0          // 7 x 131072 : text,img,neg,aw_t,aw_i,p_t,p_i [256][512]
#define SB_WT    917504     // 3 x 262144 : W_tt^T, W_it^T, W_ntt^T [512][512]
#define SB_ETP   1703936    // 2 x 65536  : eT^T, eI^T [256][256]
#define SB_CP    1835008    // 3 x 65536  : c_tt, c_it, c_nt [256][256]
#define SB_HP    2031616    // 2 x 65536  : h_t, h_i [256][256]
#define SB_PW    2162688    // 5 x 131072 : (p_t@W_tt)^T,(text@W_tt)^T,(p_i@W_it)^T,
                            //              (img@W_it)^T,(neg@W_ntt)^T  [512][256]

__device__ __forceinline__ void mfma_tiles(const short* at, const short* bt,
                                           int wr, int wc, int lane, f32x4 (&acc)[2][2]) {
  const bf16x8 fa0 = *(const bf16x8*)(at + ((wr << 1) << 9) + (lane << 3));
  const bf16x8 fa1 = *(const bf16x8*)(at + (((wr << 1) + 1) << 9) + (lane << 3));
  const bf16x8 fb0 = *(const bf16x8*)(bt + ((wc << 1) << 9) + (lane << 3));
  const bf16x8 fb1 = *(const bf16x8*)(bt + (((wc << 1) + 1) << 9) + (lane << 3));
  acc[0][0] = __builtin_amdgcn_mfma_f32_16x16x32_bf16(fa0, fb0, acc[0][0], 0, 0, 0);
  acc[0][1] = __builtin_amdgcn_mfma_f32_16x16x32_bf16(fa0, fb1, acc[0][1], 0, 0, 0);
  acc[1][0] = __builtin_amdgcn_mfma_f32_16x16x32_bf16(fa1, fb0, acc[1][0], 0, 0, 0);
  acc[1][1] = __builtin_amdgcn_mfma_f32_16x16x32_bf16(fa1, fb1, acc[1][1], 0, 0, 0);
}

__device__ __forceinline__ void reg_nt_gemm(const short* Astrip, const short* Bstrip,
                                            int ntiles, int wr, int wc, int lane,
                                            f32x4 (&acc)[2][2]) {
#pragma unroll 4
  for (int ks = 0; ks < ntiles; ++ks)
    mfma_tiles(Astrip + ks * 2048, Bstrip + ks * 2048, wr, wc, lane, acc);
}

// ---- P0: build all input panels + row inv-norms ----
__global__ __launch_bounds__(256) void p0_k(Pk p) {
  short* SH = (short*)(p.ws + WF_BF);
  const int bid = blockIdx.x, tid = threadIdx.x;
  if (bid < 28) {  // plain panels: 7 mats x 4 strips
    const int mat = bid >> 2, pr = bid & 3;
    const float* XL[7] = {p.text, p.img, p.neg, p.aw_t, p.aw_i, p.p_t, p.p_i};
    const float* X = XL[mat];
    short* Y = SH + SB_PLAIN + mat * 131072 + pr * 32768;
    const int rloc = tid >> 2, q = tid & 3;
    const int r = pr * 64 + rloc;
    float ss = 0.f;
#pragma unroll
    for (int i = 0; i < 16; ++i) {
      const int k0 = q * 8 + i * 32;
      const float4 v0 = *(const float4*)(X + (size_t)r * 512 + k0);
      const float4 v1 = *(const float4*)(X + (size_t)r * 512 + k0 + 4);
      bf16x8 pk;
      pk[0] = f2bf(v0.x); pk[1] = f2bf(v0.y); pk[2] = f2bf(v0.z); pk[3] = f2bf(v0.w);
      pk[4] = f2bf(v1.x); pk[5] = f2bf(v1.y); pk[6] = f2bf(v1.z); pk[7] = f2bf(v1.w);
      ss += v0.x*v0.x + v0.y*v0.y + v0.z*v0.z + v0.w*v0.w
          + v1.x*v1.x + v1.y*v1.y + v1.z*v1.z + v1.w*v1.w;
      *(bf16x8*)(Y + i * 2048 + ((rloc >> 4) << 9) + (q << 7) + ((rloc & 15) << 3)) = pk;
    }
    if (mat < 3) {
      ss += __shfl_xor(ss, 1, 64);
      ss += __shfl_xor(ss, 2, 64);
      if (q == 0) p.ws[WF_INV + mat * 256 + r] = 1.f / fmaxf(sqrtf(ss), 1e-12f);
    }
  } else {  // W^T panels: 3 mats x 8 strips
    const int m = (bid - 28) >> 3, pr = (bid - 28) & 7;
    const float* X = (m == 0) ? p.W_tt : (m == 1) ? p.W_it : p.W_ntt;
    short* Y = SH + SB_WT + m * 262144 + pr * 32768;
    const int lane = tid & 63, wv = tid >> 6;
    const int d = pr * 64 + lane;
#pragma unroll 2
    for (int c = 0; c < 16; ++c) {
      const int m0 = wv * 128 + c * 8;
      bf16x8 pk;
#pragma unroll
      for (int j = 0; j < 8; ++j) pk[j] = f2bf(X[(size_t)(m0 + j) * 512 + d]);
      *(bf16x8*)(Y + (m0 >> 5) * 2048 + ((lane >> 4) << 9) + (((m0 >> 3) & 3) << 7)
                 + ((lane & 15) << 3)) = pk;
    }
  }
}

// ---- S1: 8 NT GEMMs (K=512, 256x256) + 7 pre-GEMMs X@W (256x512) ----
__global__ __launch_bounds__(256) void s1_k(Pk p) {
  float* ws = p.ws;
  short* SH = (short*)(ws + WF_BF);
  const int bid = blockIdx.x, tid = threadIdx.x;
  const int lane = tid & 63, w = tid >> 6, wr = w >> 1, wc = w & 1;

  if (bid < 128) {
    const int job = bid >> 4, tile = bid & 15;
    const int bm = (tile >> 2) << 6, bn = (tile & 3) << 6;
    p.out[4 * CN * DN + bid * 256 + tid] = p.img_feature[bid * 256 + tid];

    const int AM[8] = {0, 1, 0, 2, 0, 0, 1, 0};
    const int BM[8] = {0, 1, 1, 2, 2, 3, 4, 4};
    f32x4 acc[2][2] = {};
    reg_nt_gemm(SH + SB_PLAIN + AM[job] * 131072 + (bm >> 6) * 32768,
                SH + SB_PLAIN + BM[job] * 131072 + (bn >> 6) * 32768, 16, wr, wc, lane, acc);

    float sv[2][2][4];
    if (job < 5) {
      const float* invA = ws + WF_INV + AM[job] * 256;
      const float* invB = ws + WF_INV + BM[job] * 256;
      float* C = ws + WF_S + job * 65536;
#pragma unroll
      for (int mi = 0; mi < 2; ++mi)
#pragma unroll
        for (int ni = 0; ni < 2; ++ni) {
          const int cl = (wc << 5) + (ni << 4) + (lane & 15);
#pragma unroll
          for (int jx = 0; jx < 4; ++jx) {
            const int rl = (wr << 5) + (mi << 4) + ((lane >> 4) << 2) + jx;
            const float v = acc[mi][ni][jx] * invA[bm + rl] * invB[bn + cl];
            sv[mi][ni][jx] = v;
            C[(size_t)(bm + rl) * CN + bn + cl] = v;
          }
        }
      float* rp = ws + WF_RP + job * 2048 + ((bn >> 5) + wc) * 256;
#pragma unroll
      for (int mi = 0; mi < 2; ++mi)
#pragma unroll
        for (int jx = 0; jx < 4; ++jx) {
          float s = fmaxf(sv[mi][0][jx], 0.f) + fmaxf(sv[mi][1][jx], 0.f);
          s += __shfl_xor(s, 1, 64); s += __shfl_xor(s, 2, 64);
          s += __shfl_xor(s, 4, 64); s += __shfl_xor(s, 8, 64);
          if ((lane & 15) == 0) {
            const int rl = (wr << 5) + (mi << 4) + ((lane >> 4) << 2) + jx;
            rp[bm + rl] = s;
          }
        }
    } else {
      const int z = job - 5;
      const float* bias = (job == 5) ? p.ab_t : p.ab_i;
      float* C = ws + WF_E + z * 65536;
#pragma unroll
      for (int mi = 0; mi < 2; ++mi)
#pragma unroll
        for (int ni = 0; ni < 2; ++ni) {
          const int cl = (wc << 5) + (ni << 4) + (lane & 15);
          const int rb = (wr << 5) + (mi << 4) + ((lane >> 4) << 2);
#pragma unroll
          for (int jx = 0; jx < 4; ++jx) {
            const float v = expf(acc[mi][ni][jx] + bias[bn + cl]);
            sv[mi][ni][jx] = v;
            C[(size_t)(bm + rb + jx) * CN + bn + cl] = v;
          }
          if (z < 2) {
            bf16x4 pk;
#pragma unroll
            for (int jx = 0; jx < 4; ++jx) pk[jx] = f2bf(sv[mi][ni][jx]);
            short* ET = SH + SB_ETP + z * 65536 + (bn >> 6) * 16384 + (bm >> 5) * 2048;
            const int idx = (rb >> 5) * 2048 + ((cl >> 4) << 9) + (((rb & 31) >> 3) << 7)
                          + ((cl & 15) << 3) + (rb & 7);
            *(bf16x4*)(ET + idx) = pk;
          }
        }
      if (z < 2) {
        float* ec = ws + WF_EC + z * 2048 + ((bm >> 5) + wr) * 256;
#pragma unroll
        for (int ni = 0; ni < 2; ++ni) {
          float s = 0.f;
#pragma unroll
          for (int mi = 0; mi < 2; ++mi)
#pragma unroll
            for (int jx = 0; jx < 4; ++jx) s += sv[mi][ni][jx];
          s += __shfl_xor(s, 16, 64); s += __shfl_xor(s, 32, 64);
          if ((lane >> 4) == 0) ec[bn + (wc << 5) + (ni << 4) + (lane & 15)] = s;
        }
      }
    }
  } else {
    // pre-GEMMs: X@W, 128x64 tiles (2 x 8 per job), acc[4][2]
    const int t2 = bid - 128, job = t2 >> 4, tile = t2 & 15;
    const int bm = (tile >> 3) << 7, bn = (tile & 7) << 6;
    const int AJ[7] = {5, 0, 6, 1, 0, 2, 0};
    const int WJ[7] = {0, 0, 1, 1, 1, 2, 2};
    const int TP[7] = {0, 1, 2, 3, -1, 4, -1};   // transposed-panel slot
    const int F32[7] = {-1, 0, -1, -1, 1, -1, 2}; // f32 TW slot
    const short* Astrip = SH + SB_PLAIN + AJ[job] * 131072 + ((bm >> 6) + wr) * 32768;
    const short* Bstrip = SH + SB_WT + WJ[job] * 262144 + (bn >> 6) * 32768;
    f32x4 acc[4][2] = {};
#pragma unroll 2
    for (int ks = 0; ks < 16; ++ks) {
      const short* at = Astrip + ks * 2048;
      const short* bt = Bstrip + ks * 2048;
      bf16x8 a0 = *(const bf16x8*)(at + (0 << 9) + (lane << 3));
      bf16x8 a1 = *(const bf16x8*)(at + (1 << 9) + (lane << 3));
      bf16x8 a2 = *(const bf16x8*)(at + (2 << 9) + (lane << 3));
      bf16x8 a3 = *(const bf16x8*)(at + (3 << 9) + (lane << 3));
      bf16x8 b0 = *(const bf16x8*)(bt + ((wc << 1) << 9) + (lane << 3));
      bf16x8 b1 = *(const bf16x8*)(bt + (((wc << 1) + 1) << 9) + (lane << 3));
      acc[0][0] = __builtin_amdgcn_mfma_f32_16x16x32_bf16(a0, b0, acc[0][0], 0, 0, 0);
      acc[0][1] = __builtin_amdgcn_mfma_f32_16x16x32_bf16(a0, b1, acc[0][1], 0, 0, 0);
      acc[1][0] = __builtin_amdgcn_mfma_f32_16x16x32_bf16(a1, b0, acc[1][0], 0, 0, 0);
      acc[1][1] = __builtin_amdgcn_mfma_f32_16x16x32_bf16(a1, b1, acc[1][1], 0, 0, 0);
      acc[2][0] = __builtin_amdgcn_mfma_f32_16x16x32_bf16(a2, b0, acc[2][0], 0, 0, 0);
      acc[2][1] = __builtin_amdgcn_mfma_f32_16x16x32_bf16(a2, b1, acc[2][1], 0, 0, 0);
      acc[3][0] = __builtin_amdgcn_mfma_f32_16x16x32_bf16(a3, b0, acc[3][0], 0, 0, 0);
      acc[3][1] = __builtin_amdgcn_mfma_f32_16x16x32_bf16(a3, b1, acc[3][1], 0, 0, 0);
    }
#pragma unroll
    for (int mi = 0; mi < 4; ++mi)
#pragma unroll
      for (int ni = 0; ni < 2; ++ni) {
        const int c = bn + (wc << 5) + (ni << 4) + (lane & 15);
        const int rb = bm + (wr << 6) + (mi << 4) + ((lane >> 4) << 2);
        if (TP[job] >= 0) {
          bf16x4 pk;
#pragma unroll
          for (int jx = 0; jx < 4; ++jx) pk[jx] = f2bf(acc[mi][ni][jx]);
          short* PW = SH + SB_PW + TP[job] * 131072 + (c >> 6) * 16384;
          const int idx = (rb >> 5) * 2048 + (((c & 63) >> 4) << 9) + (((rb & 31) >> 3) << 7)
                        + ((c & 15) << 3) + (rb & 7);
          *(bf16x4*)(PW + idx) = pk;
        }
        if (F32[job] >= 0) {
          float* TW = ws + WF_TW + F32[job] * 131072;
#pragma unroll
          for (int jx = 0; jx < 4; ++jx)
            TW[(size_t)(rb + jx) * DN + c] = acc[mi][ni][jx];
        }
      }
  }
}

// ---- S2: g-GEMM (c on-the-fly) + h->HP panels; cP panel builders ----
__global__ __launch_bounds__(256) void s2_k(Pk p) {
  float* ws = p.ws;
  short* SH = (short*)(ws + WF_BF);
  __shared__ __align__(16) short As[2048];
  __shared__ float srs_lds[256], d0_lds[64], E_lds[64];
  const int bid = blockIdx.x, tid = threadIdx.x;

  if (bid < 32) {
    const int job = bid >> 4, tile = bid & 15;
    const int bm = (tile >> 2) << 6, bn = (tile & 3) << 6;
    const int lane = tid & 63, w = tid >> 6, wr = w >> 1, wc = w & 1;
    const float* Araw = ws + WF_S + (job ? 2 : 0) * 65536;
    const float* e0   = ws + WF_E + (job ? 2 : 0) * 65536;
    const short* Bbase = SH + SB_ETP + job * 65536 + (bn >> 6) * 16384;
    {
      const float* rp = ws + WF_RP + (job ? 1 : 0) * 2048;
      float s = 1.f;
#pragma unroll
      for (int tc = 0; tc < 8; ++tc) s += rp[tc * 256 + tid];
      srs_lds[tid] = s;
    }
    if (tid < 64) {
      const float* rp = ws + WF_RP + (job ? 2 : 0) * 2048;
      float s = 2.f;
#pragma unroll
      for (int tc = 0; tc < 8; ++tc) s += rp[tc * 256 + bm + tid];
      d0_lds[tid] = rsqrtf(s);
    } else if (tid < 128) {
      const float* ec = ws + WF_EC + job * 2048;
      float s = 0.f;
#pragma unroll
      for (int tr = 0; tr < 8; ++tr) s += ec[tr * 256 + bn + (tid - 64)];
      E_lds[tid - 64] = s;
    }
    f32x4 acc[2][2] = {};
    for (int k0 = 0; k0 < 256; k0 += 32) {
      __syncthreads();
      const int r = tid >> 2, q = tid & 3;
      const float* pa = Araw + (size_t)(bm + r) * 256 + k0 + (q << 3);
      float x[8];
      *(float4*)&x[0] = *(const float4*)pa;
      *(float4*)&x[4] = *(const float4*)(pa + 4);
      bf16x8 pk;
#pragma unroll
      for (int i = 0; i < 8; ++i) {
        const float rv = fmaxf(x[i], 0.f);
        pk[i] = f2bf(rv * rsqrtf(srs_lds[k0 + (q << 3) + i] + rv));
      }
      *(bf16x8*)(As + ((r >> 4) << 9) + (q << 7) + ((r & 15) << 3)) = pk;
      __syncthreads();
      mfma_tiles(As, Bbase + (k0 >> 5) * 2048, wr, wc, lane, acc);
    }
    short* HP = SH + SB_HP + job * 65536 + (bm >> 6) * 16384 + (bn >> 5) * 2048;
#pragma unroll
    for (int mi = 0; mi < 2; ++mi)
#pragma unroll
      for (int ni = 0; ni < 2; ++ni) {
        const int cl = (wc << 5) + (ni << 4) + (lane & 15);
        const int rb = (wr << 5) + (mi << 4) + ((lane >> 4) << 2);
#pragma unroll
        for (int jx = 0; jx < 4; ++jx) {
          const int rl = rb + jx;
          const size_t gi = (size_t)(bm + rl) * CN + bn + cl;
          const float e = e0[gi];
          const float hv = (2.f * d0_lds[rl] * e + acc[mi][ni][jx]) / (e + E_lds[cl]);
          HP[(cl >> 5) * 2048 + ((rl >> 4) << 9) + (((cl & 31) >> 3) << 7)
             + ((rl & 15) << 3) + (cl & 7)] = f2bf(hv);
        }
      }
  } else {  // cP builders: 3 mats x 4 strips
    const int t2 = bid - 32, z = t2 >> 2, pr = t2 & 3;
    const int SRC[3] = {0, 2, 4};
    const int SRS[3] = {0, 1, 3};
    const float* src = ws + WF_S + SRC[z] * 65536;
    {
      const float* rp = ws + WF_RP + SRS[z] * 2048;
      float s = 1.f;
#pragma unroll
      for (int tc = 0; tc < 8; ++tc) s += rp[tc * 256 + tid];
      srs_lds[tid] = s;
    }
    __syncthreads();
    short* Y = SH + SB_CP + z * 65536 + pr * 16384;
    const int rloc = tid >> 2, q = tid & 3, r = pr * 64 + rloc;
#pragma unroll
    for (int i = 0; i < 8; ++i) {
      const int k0 = q * 8 + i * 32;
      float x[8];
      *(float4*)&x[0] = *(const float4*)(src + (size_t)r * 256 + k0);
      *(float4*)&x[4] = *(const float4*)(src + (size_t)r * 256 + k0 + 4);
      bf16x8 pk;
#pragma unroll
      for (int j = 0; j < 8; ++j) {
        const float rv = fmaxf(x[j], 0.f);
        pk[j] = f2bf(rv * rsqrtf(srs_lds[k0 + j] + rv));
      }
      *(bf16x8*)(Y + i * 2048 + ((rloc >> 4) << 9) + (q << 7) + ((rloc & 15) << 3)) = pk;
    }
  }
}

// ---- S3: out = tanh(d0*(h@PW + c@XW + 2*d0*TW) + bias); job3 = main ----
__global__ __launch_bounds__(256) void s3_k(Pk p) {
  float* ws = p.ws;
  short* SH = (short*)(ws + WF_BF);
  __shared__ float d0a[64], d0b[64];
  const int bid = blockIdx.x, tid = threadIdx.x;
  const int job = bid >> 5, t = bid & 31;
  const int bm = (t >> 3) << 6, bn = (t & 7) << 6;
  const int lane = tid & 63, w = tid >> 6, wr = w >> 1, wc = w & 1;
  const int D0A[4] = {0, 2, 4, 0};
  if (tid < 64) {
    const float* rp = ws + WF_RP + D0A[job] * 2048;
    float s = 2.f;
#pragma unroll
    for (int tc = 0; tc < 8; ++tc) s += rp[tc * 256 + bm + tid];
    d0a[tid] = rsqrtf(s);
    if (job == 3) {
      const float* rp2 = ws + WF_RP + 2 * 2048;
      float s2 = 2.f;
#pragma unroll
      for (int tc = 0; tc < 8; ++tc) s2 += rp2[tc * 256 + bm + tid];
      d0b[tid] = rsqrtf(s2);
    }
  }
  __syncthreads();

  const int mstrip = bm >> 6, nstrip = bn >> 6;
  if (job < 3) {
    const float* bias = (job == 0) ? p.b_tt : (job == 1) ? p.b_it : p.b_ntt;
    const float* TW = ws + WF_TW + job * 131072;
    float* O = p.out + (size_t)(job + 1) * CN * DN;
    f32x4 acc[2][2] = {};
    if (job == 0) {
      reg_nt_gemm(SH + SB_HP + mstrip * 16384, SH + SB_PW + nstrip * 16384, 8, wr, wc, lane, acc);
      reg_nt_gemm(SH + SB_CP + mstrip * 16384, SH + SB_PW + 131072 + nstrip * 16384, 8, wr, wc, lane, acc);
    } else if (job == 1) {
      reg_nt_gemm(SH + SB_HP + 65536 + mstrip * 16384, SH + SB_PW + 2 * 131072 + nstrip * 16384, 8, wr, wc, lane, acc);
      reg_nt_gemm(SH + SB_CP + 65536 + mstrip * 16384, SH + SB_PW + 3 * 131072 + nstrip * 16384, 8, wr, wc, lane, acc);
    } else {
      reg_nt_gemm(SH + SB_CP + 131072 + mstrip * 16384, SH + SB_PW + 4 * 131072 + nstrip * 16384, 8, wr, wc, lane, acc);
    }
#pragma unroll
    for (int mi = 0; mi < 2; ++mi)
#pragma unroll
      for (int ni = 0; ni < 2; ++ni) {
        const int cl = (wc << 5) + (ni << 4) + (lane & 15);
        const int rb = (wr << 5) + (mi << 4) + ((lane >> 4) << 2);
#pragma unroll
        for (int jx = 0; jx < 4; ++jx) {
          const int rl = rb + jx;
          const size_t idx = (size_t)(bm + rl) * DN + bn + cl;
          const float d = d0a[rl];
          O[idx] = tanhf(d * (acc[mi][ni][jx] + 2.f * d * TW[idx]) + bias[idx]);
        }
      }
  } else {
    f32x4 acc1[2][2] = {}, acc2[2][2] = {};
    reg_nt_gemm(SH + SB_HP + mstrip * 16384, SH + SB_PW + nstrip * 16384, 8, wr, wc, lane, acc1);
    reg_nt_gemm(SH + SB_CP + mstrip * 16384, SH + SB_PW + 131072 + nstrip * 16384, 8, wr, wc, lane, acc1);
    reg_nt_gemm(SH + SB_HP + 65536 + mstrip * 16384, SH + SB_PW + 2 * 131072 + nstrip * 16384, 8, wr, wc, lane, acc2);
    reg_nt_gemm(SH + SB_CP + 65536 + mstrip * 16384, SH + SB_PW + 3 * 131072 + nstrip * 16384, 8, wr, wc, lane, acc2);
    const float* TWtt = ws + WF_TW;
    const float* TWit = ws + WF_TW + 131072;
#pragma unroll
    for (int mi = 0; mi < 2; ++mi)
#pragma unroll
      for (int ni = 0; ni < 2; ++ni) {
        const int cl = (wc << 5) + (ni << 4) + (lane & 15);
        const int rb = (wr << 5) + (mi << 4) + ((lane >> 4) << 2);
#pragma unroll
        for (int jx = 0; jx < 4; ++jx) {
          const int rl = rb + jx;
          const size_t idx = (size_t)(bm + rl) * DN + bn + cl;
          const float da = d0a[rl], db = d0b[rl];
          const float ott = tanhf(da * (acc1[mi][ni][jx] + 2.f * da * TWtt[idx]) + p.b_tt[idx]);
          const float oit = tanhf(db * (acc2[mi][ni][jx] + 2.f * db * TWit[idx]) + p.b_it[idx]);
          p.out[idx] = 0.5f * p.text[idx] + 0.35f * ott + 0.15f * oit;
        }
      }
  }
}

extern "C" void kernel_launch(void* const* d_in, const int* in_sizes, int n_in,
                              void* d_out, int out_size, void* d_ws, size_t ws_size,
                              hipStream_t stream) {
  Pk prm;
  prm.img_feature = (const float*)d_in[0];
  prm.text  = (const float*)d_in[1];
  prm.img   = (const float*)d_in[2];
  prm.neg   = (const float*)d_in[3];
  prm.p_t   = (const float*)d_in[4];
  prm.aw_t  = (const float*)d_in[5];
  prm.ab_t  = (const float*)d_in[6];
  prm.p_i   = (const float*)d_in[7];
  prm.aw_i  = (const float*)d_in[8];
  prm.ab_i  = (const float*)d_in[9];
  prm.W_tt  = (const float*)d_in[10];
  prm.b_tt  = (const float*)d_in[11];
  prm.W_it  = (const float*)d_in[12];
  prm.b_it  = (const float*)d_in[13];
  prm.W_ntt = (const float*)d_in[14];
  prm.b_ntt = (const float*)d_in[15];
  prm.out = (float*)d_out;
  prm.ws  = (float*)d_ws;

  p0_k<<<52, 256, 0, stream>>>(prm);
  s1_k<<<240, 256, 0, stream>>>(prm);
  s2_k<<<44, 256, 0, stream>>>(prm);
  s3_k<<<128, 256, 0, stream>>>(prm);
}